// Round 1
// baseline (253.624 us; speedup 1.0000x reference)
//
#include <hip/hip_runtime.h>

#define B_ 8
#define C_ 32
#define NI 256   // coarse positions (16x16)
#define T_ 256   // sub-block offsets
#define C4 8192  // merged channels = 32*256

typedef _Float16 f16;
typedef __attribute__((ext_vector_type(8))) _Float16 f16x8;
typedef __attribute__((ext_vector_type(4))) _Float16 f16x4;
typedef __attribute__((ext_vector_type(4))) float f32x4;

__device__ __forceinline__ int dh_of(int t) { return (t & 1) | ((t >> 1) & 2) | ((t >> 2) & 4) | ((t >> 3) & 8); }
__device__ __forceinline__ int dw_of(int t) { return ((t >> 1) & 1) | ((t >> 2) & 2) | ((t >> 3) & 4) | ((t >> 4) & 8); }

// ---------------------------------------------------------------------------
// K1: depthwise 3x3 conv (Q,K) + identity (V), permuted to [b][i][c4] f16.
// block = (b, i); 256 threads; thread t handles sub-offset t, loops 32 channels.
// ---------------------------------------------------------------------------
__global__ __launch_bounds__(256) void k1_conv_permute(
    const float* __restrict__ x, const float* __restrict__ wq, const float* __restrict__ bq,
    const float* __restrict__ wk, const float* __restrict__ bk,
    f16* __restrict__ Qt, f16* __restrict__ Kt, f16* __restrict__ Vt)
{
  __shared__ float xs[C_ * 324];  // 32 x 18 x 18
  __shared__ float wqs[C_ * 9], wks[C_ * 9], bqs[C_], bks[C_];
  const int bid = blockIdx.x;
  const int b = bid >> 8, i = bid & 255;
  const int hi = i >> 4, wi = i & 15;
  const int tid = threadIdx.x;

  for (int idx = tid; idx < 288; idx += 256) { wqs[idx] = wq[idx]; wks[idx] = wk[idx]; }
  if (tid < 32) { bqs[tid] = bq[tid]; bks[tid] = bk[tid]; }

  const int h0 = hi * 16 - 1, w0 = wi * 16 - 1;
  for (int idx = tid; idx < C_ * 324; idx += 256) {
    const int c = idx / 324;
    const int rem = idx - c * 324;
    const int r = rem / 18, col = rem - r * 18;
    const int gh = h0 + r, gw = w0 + col;
    float v = 0.f;
    if ((unsigned)gh < 256u && (unsigned)gw < 256u)
      v = x[(((size_t)(b * C_ + c) << 8) + gh) * 256 + gw];
    xs[idx] = v;
  }
  __syncthreads();

  const int t = tid;
  const int dh = dh_of(t), dw = dw_of(t);
  f16x8 qv[4], kv[4], vv[4];
#pragma unroll
  for (int c = 0; c < 32; ++c) {
    const float* ts = &xs[c * 324 + dh * 18 + dw];
    float q = bqs[c], k = bks[c];
#pragma unroll
    for (int dy = 0; dy < 3; ++dy)
#pragma unroll
      for (int dx = 0; dx < 3; ++dx) {
        const float v = ts[dy * 18 + dx];
        q += v * wqs[c * 9 + dy * 3 + dx];
        k += v * wks[c * 9 + dy * 3 + dx];
      }
    qv[c >> 3][c & 7] = (f16)q;
    kv[c >> 3][c & 7] = (f16)k;
    vv[c >> 3][c & 7] = (f16)ts[19];  // center tap (dh+1, dw+1) -> +18+1
  }
  const size_t off = ((size_t)(b * NI + i)) * C4 + (size_t)t * 32;
  f16x8* Qp = (f16x8*)(Qt + off);
  f16x8* Kp = (f16x8*)(Kt + off);
  f16x8* Vp = (f16x8*)(Vt + off);
#pragma unroll
  for (int s = 0; s < 4; ++s) { Qp[s] = qv[s]; Kp[s] = kv[s]; Vp[s] = vv[s]; }
}

// ---------------------------------------------------------------------------
// K2: logits partials. S[b,i,j] = sum_c4 Qt[b,i,c4]*Kt[b,j,c4], split-K by 4.
// grid (16 tiles, 4 ksplit, 8 batch); 4 waves: wave = 16 i-rows x 64 j-cols.
// ---------------------------------------------------------------------------
__global__ __launch_bounds__(256) void k2_logits(
    const f16* __restrict__ Qt, const f16* __restrict__ Kt, float* __restrict__ Spart)
{
  const int b = blockIdx.z;
  const int kt = blockIdx.y;
  const int it = blockIdx.x >> 2, jt = blockIdx.x & 3;
  const int tid = threadIdx.x, wave = tid >> 6, lane = tid & 63;
  const int li = lane & 15, lk = lane >> 4;
  const int i0 = it * 64 + wave * 16;
  const int j0 = jt * 64;
  const f16* Qb = Qt + (size_t)b * NI * C4;
  const f16* Kb = Kt + (size_t)b * NI * C4;

  f32x4 acc[4] = {};
  const int kbeg = kt * 2048, kend = kbeg + 2048;
  for (int k = kbeg; k < kend; k += 32) {
    const f16x8 a = *(const f16x8*)(Qb + (size_t)(i0 + li) * C4 + k + lk * 8);
#pragma unroll
    for (int jj = 0; jj < 4; ++jj) {
      const f16x8 bb = *(const f16x8*)(Kb + (size_t)(j0 + jj * 16 + li) * C4 + k + lk * 8);
      acc[jj] = __builtin_amdgcn_mfma_f32_16x16x32_f16(a, bb, acc[jj], 0, 0, 0);
    }
  }
  float* Sp = Spart + ((size_t)kt * B_ + b) * NI * NI;
#pragma unroll
  for (int jj = 0; jj < 4; ++jj)
#pragma unroll
    for (int r = 0; r < 4; ++r) {
      const int ii = i0 + lk * 4 + r;
      const int jc = j0 + jj * 16 + li;
      Sp[(size_t)ii * NI + jc] = acc[jj][r];
    }
}

// ---------------------------------------------------------------------------
// K3: sum 4 partials + softmax over j (256), write f16. One wave per row.
// ---------------------------------------------------------------------------
__global__ __launch_bounds__(256) void k3_softmax(
    const float* __restrict__ Spart, f16* __restrict__ Sh)
{
  const int row = blockIdx.x * 4 + (threadIdx.x >> 6);  // 2048 rows
  const int lane = threadIdx.x & 63;
  const size_t base = (size_t)row * NI + lane * 4;
  f32x4 v = {0.f, 0.f, 0.f, 0.f};
#pragma unroll
  for (int kt = 0; kt < 4; ++kt) {
    const f32x4 p = *(const f32x4*)(Spart + (size_t)kt * B_ * NI * NI + base);
    v[0] += p[0]; v[1] += p[1]; v[2] += p[2]; v[3] += p[3];
  }
  float m = fmaxf(fmaxf(v[0], v[1]), fmaxf(v[2], v[3]));
#pragma unroll
  for (int d = 1; d < 64; d <<= 1) m = fmaxf(m, __shfl_xor(m, d, 64));
  const float e0 = expf(v[0] - m), e1 = expf(v[1] - m), e2 = expf(v[2] - m), e3 = expf(v[3] - m);
  float s = e0 + e1 + e2 + e3;
#pragma unroll
  for (int d = 1; d < 64; d <<= 1) s += __shfl_xor(s, d, 64);
  const float inv = 1.f / s;
  f16x4 o;
  o[0] = (f16)(e0 * inv); o[1] = (f16)(e1 * inv); o[2] = (f16)(e2 * inv); o[3] = (f16)(e3 * inv);
  *(f16x4*)(Sh + (size_t)row * NI + lane * 4) = o;
}

// ---------------------------------------------------------------------------
// K4: E[c4,i] = sum_j V[c4,j]*S[i,j]; Y = E + V (residual), f16 [b][i][c4].
// block = (b, t): V-panel = rows t*32..t*32+31; LDS-transpose from Vt.
// 4 waves, each owns 64 i-columns; M=32 (2 tiles) x K=256 (8 steps).
// ---------------------------------------------------------------------------
__global__ __launch_bounds__(256) void k4_ev(
    const f16* __restrict__ Vt, const f16* __restrict__ Sh, f16* __restrict__ Y)
{
  __shared__ f16 Vs[32 * 264];  // [ci][i], padded stride 264
  const int bid = blockIdx.x;
  const int b = bid >> 8, t = bid & 255;
  const int tid = threadIdx.x;

  {  // transpose-stage: thread tid = column i
    const f16x8* src = (const f16x8*)(Vt + ((size_t)(b * NI + tid)) * C4 + (size_t)t * 32);
    const f16x8 v0 = src[0], v1 = src[1], v2 = src[2], v3 = src[3];
#pragma unroll
    for (int e = 0; e < 8; ++e) {
      Vs[(0 + e) * 264 + tid] = v0[e];
      Vs[(8 + e) * 264 + tid] = v1[e];
      Vs[(16 + e) * 264 + tid] = v2[e];
      Vs[(24 + e) * 264 + tid] = v3[e];
    }
  }
  __syncthreads();

  const int wave = tid >> 6, lane = tid & 63, li = lane & 15, lk = lane >> 4;
  const int i0 = wave * 64;
  const f16* Shb = Sh + (size_t)b * NI * NI;

  f32x4 acc[2][4] = {};
#pragma unroll
  for (int ks = 0; ks < 8; ++ks) {
    const int k = ks * 32 + lk * 8;
    const f16x8 a0 = *(const f16x8*)(&Vs[li * 264 + k]);
    const f16x8 a1 = *(const f16x8*)(&Vs[(16 + li) * 264 + k]);
#pragma unroll
    for (int ct = 0; ct < 4; ++ct) {
      const f16x8 bb = *(const f16x8*)(Shb + (size_t)(i0 + ct * 16 + li) * NI + k);
      acc[0][ct] = __builtin_amdgcn_mfma_f32_16x16x32_f16(a0, bb, acc[0][ct], 0, 0, 0);
      acc[1][ct] = __builtin_amdgcn_mfma_f32_16x16x32_f16(a1, bb, acc[1][ct], 0, 0, 0);
    }
  }
#pragma unroll
  for (int mt = 0; mt < 2; ++mt)
#pragma unroll
    for (int ct = 0; ct < 4; ++ct)
#pragma unroll
      for (int r = 0; r < 4; ++r) {
        const int ci = mt * 16 + lk * 4 + r;
        const int ii = i0 + ct * 16 + li;
        const float y = acc[mt][ct][r] + (float)Vs[ci * 264 + ii];
        Y[((size_t)(b * NI + ii)) * C4 + (size_t)t * 32 + ci] = (f16)y;
      }
}

// ---------------------------------------------------------------------------
// K5: out[b,o,h,w] = sum_ci w1[o,ci] * Y[b, i(h,w), t(h,w)*32+ci], fp32 out.
// block = (b, i): GEMM (256 t-rows x 32 o-cols, K=32) via MFMA; scatter store.
// ---------------------------------------------------------------------------
__global__ __launch_bounds__(256) void k5_w1_unpermute(
    const f16* __restrict__ Y, const float* __restrict__ w1, float* __restrict__ out)
{
  __shared__ f16 w1s[32 * 32];
  const int bid = blockIdx.x;
  const int b = bid >> 8, i = bid & 255;
  const int hi = i >> 4, wi = i & 15;
  const int tid = threadIdx.x;
#pragma unroll
  for (int e = 0; e < 4; ++e) w1s[tid + 256 * e] = (f16)w1[tid + 256 * e];
  __syncthreads();

  const int wave = tid >> 6, lane = tid & 63, li = lane & 15, lk = lane >> 4;
  const f16* Yrow = Y + ((size_t)(b * NI + i)) * C4;
  const f16x8 b0 = *(const f16x8*)(&w1s[li * 32 + lk * 8]);         // o = li
  const f16x8 b1 = *(const f16x8*)(&w1s[(16 + li) * 32 + lk * 8]);  // o = 16+li

#pragma unroll
  for (int q = 0; q < 4; ++q) {
    const int tt = wave * 4 + q;
    const f16x8 a = *(const f16x8*)(Yrow + (size_t)(tt * 16 + li) * 32 + lk * 8);
    f32x4 d0 = {}, d1 = {};
    d0 = __builtin_amdgcn_mfma_f32_16x16x32_f16(a, b0, d0, 0, 0, 0);
    d1 = __builtin_amdgcn_mfma_f32_16x16x32_f16(a, b1, d1, 0, 0, 0);
#pragma unroll
    for (int r = 0; r < 4; ++r) {
      const int t = tt * 16 + lk * 4 + r;
      const int dh = dh_of(t), dw = dw_of(t);
      const int h = hi * 16 + dh, w = wi * 16 + dw;
      out[(((size_t)(b * 32 + li)) * 256 + h) * 256 + w] = d0[r];
      out[(((size_t)(b * 32 + 16 + li)) * 256 + h) * 256 + w] = d1[r];
    }
  }
}

// ---------------------------------------------------------------------------
extern "C" void kernel_launch(void* const* d_in, const int* in_sizes, int n_in,
                              void* d_out, int out_size, void* d_ws, size_t ws_size,
                              hipStream_t stream)
{
  const float* x  = (const float*)d_in[0];
  const float* wq = (const float*)d_in[1];
  const float* bq = (const float*)d_in[2];
  const float* wk = (const float*)d_in[3];
  const float* bk = (const float*)d_in[4];
  const float* w1 = (const float*)d_in[5];
  float* out = (float*)d_out;
  char* ws = (char*)d_ws;

  // ws layout (bytes):
  //   Qt [0, 32M)            -- reused as Y after K2
  //   Kt [32M, 64M)
  //   Vt [64M, 96M)
  //   Spart [96M, 104M)
  //   Sh [104M, 105M)
  f16*   Qt    = (f16*)(ws);
  f16*   Kt    = (f16*)(ws + 33554432);
  f16*   Vt    = (f16*)(ws + 67108864);
  float* Spart = (float*)(ws + 100663296);
  f16*   Sh    = (f16*)(ws + 109051904);
  f16*   Y     = Qt;  // Qt dead after K2

  k1_conv_permute<<<2048, 256, 0, stream>>>(x, wq, bq, wk, bk, Qt, Kt, Vt);
  k2_logits<<<dim3(16, 4, 8), 256, 0, stream>>>(Qt, Kt, Spart);
  k3_softmax<<<512, 256, 0, stream>>>(Spart, Sh);
  k4_ev<<<2048, 256, 0, stream>>>(Vt, Sh, Y);
  k5_w1_unpermute<<<2048, 256, 0, stream>>>(Y, w1, out);
}